// Round 6
// baseline (506.768 us; speedup 1.0000x reference)
//
#include <hip/hip_runtime.h>
#include <hip/hip_fp16.h>

// GCN link-prediction forward. Slice-major (L2-resident per XCD) gather tables
// for BOTH aggregates and decode: g1s[8][N][32], h1s[8][N][32], g2s[4][N][32],
// zs[4][N][32] f16 (3.2MB/slice < 4MB L2/XCD; slice pinned via blockIdx&mask).
// Aggregates are wave-per-(node,slice), 16 edges/gather-instr, xor-reduce.
// Decode: R0 TA-floor form (32 edges/wave, 2 lanes/edge), split into pos/neg
// launches (diagnostic unmasking); psum + nontemporal + dsum (atomics slower,
// measured R4). fp16 MFMA GEMMs with slice-major epilogue (SWL=5); fused prep;
// scan2 folded into scan3.
// Inputs: x[N,256] f32, train_edges[2,E] i32, pos[2,E] i32, neg[2,E] i32,
//         W1[256,256], b1[256], W2[256,128], b2[128]  (all f32)
// Output: logits[2E] f32.

#define NFEAT 256
#define HID   256
#define OUTF  128

typedef _Float16 f16x8 __attribute__((ext_vector_type(8)));
typedef _Float16 f16x2 __attribute__((ext_vector_type(2)));
typedef float    f32x4 __attribute__((ext_vector_type(4)));

// ---------------- W transpose tile body: Wt[m][k] = (half)W[k][m] ------------
__device__ __forceinline__ void wt_body(const float* __restrict__ W,
                                        __half* __restrict__ Wt,
                                        int K, int M, int bxx, int byy) {
    __shared__ float tile[32][33];
    int k0 = bxx * 32, m0 = byy * 32;
    int tx = threadIdx.x & 31, ty = threadIdx.x >> 5;  // ty 0..7
#pragma unroll
    for (int r = 0; r < 4; ++r)
        tile[ty + r * 8][tx] = W[(size_t)(k0 + ty + r * 8) * M + m0 + tx];
    __syncthreads();
#pragma unroll
    for (int r = 0; r < 4; ++r)
        Wt[(size_t)(m0 + ty + r * 8) * K + k0 + tx] = __float2half(tile[tx][ty + r * 8]);
}

// ---------------- fused prep: wt(W1) | wt(W2) | deg=1 ----------------
__global__ __launch_bounds__(256) void k_prep(
        const float* __restrict__ W1, __half* __restrict__ W1t,
        const float* __restrict__ W2, __half* __restrict__ W2t,
        float* __restrict__ deg, int n) {
    int bid = blockIdx.x;
    if (bid < 64) { wt_body(W1, W1t, NFEAT, HID, bid & 7, bid >> 3); return; }
    bid -= 64;
    if (bid < 32) { wt_body(W2, W2t, HID, OUTF, bid & 7, bid >> 3); return; }
    bid -= 32;
    int i = bid * 256 + threadIdx.x;
    if (i < n) deg[i] = 1.0f;   // self-loop
}

// ---------------- degree count ----------------
__global__ void k_count_deg(const int* __restrict__ ei, float* __restrict__ deg, int E) {
    int e = blockIdx.x * blockDim.x + threadIdx.x;
    if (e < E) atomicAdd(&deg[ei[E + e]], 1.0f);   // dst row
}

// ---------------- parallel scan, pass 1: per-block exclusive scan ------------
// bsum[b] gets the RAW per-block total (scan of totals happens in k_scan3).
__global__ __launch_bounds__(1024) void k_scan1(
        const float* __restrict__ deg, int* __restrict__ excl,
        int* __restrict__ bsum, int n) {
    __shared__ int swsum[16];
    const int t = threadIdx.x, wave = t >> 6, lane = t & 63;
    const int i = blockIdx.x * 1024 + t;
    int v = (i < n) ? (int)deg[i] - 1 : 0;
    int sc = v;
#pragma unroll
    for (int off = 1; off < 64; off <<= 1) {
        int y = __shfl_up(sc, off);
        if (lane >= off) sc += y;
    }
    if (lane == 63) swsum[wave] = sc;
    __syncthreads();
    if (t < 16) {
        int w = swsum[t];
        int scw = w;
#pragma unroll
        for (int off = 1; off < 16; off <<= 1) {
            int y = __shfl_up(scw, off);
            if (t >= off) scw += y;
        }
        swsum[t] = scw - w;
        if (t == 15) bsum[blockIdx.x] = scw;
    }
    __syncthreads();
    if (i < n) excl[i] = swsum[wave] + (sc - v);
}

// ---------------- pass 2 (fused): rowptr/cursor/dinv; lanes re-scan bsum -----
__global__ __launch_bounds__(256) void k_scan3(
        float* __restrict__ deg_dinv, const int* __restrict__ excl,
        const int* __restrict__ bsum, int* __restrict__ rowptr,
        int* __restrict__ cursor, int n, int nb) {
    __shared__ int pbs[65];
    const int t = threadIdx.x;
    if (t < 64) {
        int v = (t < nb) ? bsum[t] : 0;
        int sc = v;
#pragma unroll
        for (int off = 1; off < 64; off <<= 1) {
            int y = __shfl_up(sc, off);
            if (t >= off) sc += y;
        }
        pbs[t] = sc - v;            // exclusive prefix of block totals
        if (t == 63) pbs[64] = sc;  // grand total
    }
    __syncthreads();
    int i = blockIdx.x * 256 + t;
    if (i < n) {
        int rp = excl[i] + pbs[i >> 10];
        rowptr[i] = rp;
        cursor[i] = rp;
        deg_dinv[i] = rsqrtf(deg_dinv[i]);
    } else if (i == n) {
        rowptr[n] = pbs[64];
    }
}

// ---------------- fill CSR adjacency (src ids grouped by dst) ----------------
__global__ void k_fill(const int* __restrict__ ei, int* __restrict__ cursor,
                       int* __restrict__ eidx, int E) {
    int e = blockIdx.x * blockDim.x + threadIdx.x;
    if (e < E) {
        int s = ei[e];
        int d = ei[E + e];
        int p = atomicAdd(&cursor[d], 1);
        eidx[p] = s;
    }
}

// ---------------- MFMA GEMM: out = (half)(dinv[r] * A @ Wt^T), sliced out ----
// Block: 256 threads = 4 waves (2x2). Block tile (2*MT*16) x 128, wave (MT*16) x 64.
// A: f32 row-major if AF32; f16 sliced [K/32][n][32] if ASL; else f16 row-major.
// Wt: [M][K] f16. K % 32 == 0. SWL=5 -> output sliced [M/32][n][32].
template <int MT, bool AF32, bool ASL, int SWL>
__global__ __launch_bounds__(256) void k_gemm_mfma(
        const void* __restrict__ Aptr, const __half* __restrict__ Wt,
        const float* __restrict__ dinv, __half* __restrict__ outp,
        int n, int K, int M) {
    constexpr int BM = 2 * MT * 16;
    __shared__ __half As[BM][40];      // [row][k], +8 pad: 2-way banks (free)
    __shared__ __half Bs[128][40];     // [col][k]
    __shared__ __half Cs[4][16][72];   // per-wave C repack (16B-aligned rows)

    const int t    = threadIdx.x;
    const int wave = t >> 6;
    const int lane = t & 63;
    const int row0 = blockIdx.x * BM;
    const int col0 = blockIdx.y * 128;
    const int wm = wave >> 1, wn = wave & 1;
    const int lr = lane & 15;          // fragment m/n index
    const int kq = lane >> 4;          // k-quad: k = kq*8 + j

    f32x4 acc[MT][4];
#pragma unroll
    for (int i = 0; i < MT; ++i)
#pragma unroll
        for (int j = 0; j < 4; ++j) acc[i][j] = (f32x4){0.f, 0.f, 0.f, 0.f};

    for (int k0 = 0; k0 < K; k0 += 32) {
        // ---- stage A tile: BM rows x 32 k ----
        if (AF32) {
            const float* A = (const float*)Aptr;
#pragma unroll
            for (int it = 0; it < BM * 8 / 256; ++it) {
                int q = t + it * 256;
                int r = q >> 3, c4 = q & 7;       // c4: which 4-float chunk
                int gr = min(row0 + r, n - 1);
                float4 v = *(const float4*)&A[(size_t)gr * K + k0 + c4 * 4];
                __half2* dst = (__half2*)&As[r][c4 * 4];
                dst[0] = __floats2half2_rn(v.x, v.y);
                dst[1] = __floats2half2_rn(v.z, v.w);
            }
        } else {
            const __half* A = (const __half*)Aptr;
#pragma unroll
            for (int it = 0; it < BM * 4 / 256; ++it) {
                int q = t + it * 256;
                int r = q >> 2, c8 = q & 3;       // c8: which 8-half chunk
                int gr = min(row0 + r, n - 1);
                size_t aidx;
                if (ASL) {
                    int kk = k0 + c8 * 8;          // multiple of 8, one slice
                    aidx = ((size_t)(kk >> 5) * n + gr) * 32 + (kk & 31);
                } else {
                    aidx = (size_t)gr * K + k0 + c8 * 8;
                }
                *(float4*)&As[r][c8 * 8] = *(const float4*)&A[aidx];
            }
        }
        // ---- stage B tile: 128 cols x 32 k from Wt ----
#pragma unroll
        for (int it = 0; it < 2; ++it) {
            int q = t + it * 256;
            int r = q >> 2, c8 = q & 3;
            *(float4*)&Bs[r][c8 * 8] = *(const float4*)&Wt[(size_t)(col0 + r) * K + k0 + c8 * 8];
        }
        __syncthreads();

        f16x8 b[4];
#pragma unroll
        for (int j = 0; j < 4; ++j)
            b[j] = *(const f16x8*)&Bs[wn * 64 + j * 16 + lr][kq * 8];
#pragma unroll
        for (int i = 0; i < MT; ++i) {
            f16x8 a = *(const f16x8*)&As[wm * MT * 16 + i * 16 + lr][kq * 8];
#pragma unroll
            for (int j = 0; j < 4; ++j)
                acc[i][j] = __builtin_amdgcn_mfma_f32_16x16x32_f16(a, b[j], acc[i][j], 0, 0, 0);
        }
        __syncthreads();
    }

    // ---- epilogue: scale by dinv, f16 convert, repack via LDS, 16-B stores ----
    constexpr int SW = 1 << SWL;
#pragma unroll
    for (int i = 0; i < MT; ++i) {
        int gr0 = row0 + wm * MT * 16 + i * 16;
        float dv[4];
#pragma unroll
        for (int r = 0; r < 4; ++r)
            dv[r] = dinv[min(gr0 + kq * 4 + r, n - 1)];
        __syncthreads();   // protect Cs reuse across i iterations
#pragma unroll
        for (int j = 0; j < 4; ++j)
#pragma unroll
            for (int r = 0; r < 4; ++r)
                Cs[wave][kq * 4 + r][j * 16 + lr] = __float2half(acc[i][j][r] * dv[r]);
        __syncthreads();
        int r1 = lane >> 3, c1 = (lane & 7) * 8;
#pragma unroll
        for (int h = 0; h < 2; ++h) {
            int grow = gr0 + r1 + h * 8;
            if (grow < n) {
                int col = col0 + wn * 64 + c1;    // multiple of 8, within a slice
                size_t oidx = ((size_t)(col >> SWL) * n + grow) * SW + (col & (SW - 1));
                *(float4*)&outp[oidx] = *(const float4*)&Cs[wave][r1 + h * 8][c1];
            }
        }
    }
}

// ---------------- slice-parallel aggregate: wave per (node, slice) -----------
// g sliced [NS][n][32] f16 (64B rows, 3.2MB/slice = L2-resident/XCD).
// lane = eo*4 + c: eo = edge slot (0..15), c = 16B chunk. 16 edges/instr.
// RELU: layer-1 (bias+relu, out h1s); else layer-2 (bias, out zs). Self row
// counted once via eo==0. Reduce over eo via xor 4/8/16/32.
template <int NS, bool RELU>
__global__ __launch_bounds__(256) void k_aggs(
        const int* __restrict__ rowptr, const int* __restrict__ eidx,
        const __half* __restrict__ g, const float* __restrict__ dinv,
        const float* __restrict__ bias, __half* __restrict__ out, int n) {
    const int slice = blockIdx.x & (NS - 1);
    const int node  = (int)(((size_t)(blockIdx.x >> (NS == 8 ? 3 : 2)) * 4) + (threadIdx.x >> 6));
    const int lane  = threadIdx.x & 63;
    const int eo    = lane >> 2;       // edge slot within wave (0..15)
    const int c     = lane & 3;        // 16B chunk within 64B slice row
    if (node >= n) return;
    const __half* gs = g + (size_t)slice * n * 32;
    const int j0  = rowptr[node];
    const int end = rowptr[node + 1];
    const int last = end - 1;

    union U { float4 f; __half2 h[4]; };
    float acc[8] = {0.f, 0.f, 0.f, 0.f, 0.f, 0.f, 0.f, 0.f};
    if (eo == 0) {   // self row (once)
        U u; u.f = *(const float4*)&gs[(size_t)node * 32 + c * 8];
#pragma unroll
        for (int k = 0; k < 4; ++k) {
            float2 v = __half22float2(u.h[k]);
            acc[k * 2] += v.x; acc[k * 2 + 1] += v.y;
        }
    }
    if (j0 < end) {
        int s0 = eidx[min(j0 + eo, last)];
        for (int j = j0; j < end; j += 16) {
            int p0 = eidx[min(j + 16 + eo, last)];   // prefetch next iter
            U u; u.f = *(const float4*)&gs[(size_t)s0 * 32 + c * 8];
            if (j + eo < end) {
#pragma unroll
                for (int k = 0; k < 4; ++k) {
                    float2 v = __half22float2(u.h[k]);
                    acc[k * 2] += v.x; acc[k * 2 + 1] += v.y;
                }
            }
            s0 = p0;
        }
    }
    // reduce over edge slots (lane bits 5:2)
#pragma unroll
    for (int k = 0; k < 8; ++k) {
        acc[k] += __shfl_xor(acc[k], 4);
        acc[k] += __shfl_xor(acc[k], 8);
        acc[k] += __shfl_xor(acc[k], 16);
        acc[k] += __shfl_xor(acc[k], 32);
    }
    if (eo == 0) {
        const float sc = dinv[node];
        const int f0 = slice * 32 + c * 8;
        U r;
#pragma unroll
        for (int k = 0; k < 4; ++k) {
            float2 bb = *(const float2*)&bias[f0 + k * 2];
            float x0 = sc * acc[k * 2]     + bb.x;
            float x1 = sc * acc[k * 2 + 1] + bb.y;
            if (RELU) { x0 = fmaxf(x0, 0.f); x1 = fmaxf(x1, 0.f); }
            r.h[k] = __floats2half2_rn(x0, x1);
        }
        *(float4*)&out[((size_t)slice * n + node) * 32 + c * 8] = r.f;
    }
}

// ---------------- decode (sliced): psum[slice][e], 32 edges/wave -------------
// zs [4][n][32] f16; slice = bx & 3 (XCD-pinned, 3.2MB L2-resident).
// lane = (edge-in-wave)*2 + h; lane loads 32B of BOTH endpoint rows, 16-feat
// dot. ebase splits the launch into pos/neg halves (diagnostic + uniform branch).
__global__ __launch_bounds__(256) void k_decode(
        const int* __restrict__ pos, const int* __restrict__ neg,
        const __half* __restrict__ zs, float* __restrict__ psum,
        int E, int n, int ebase) {
    const int slice = blockIdx.x & 3;
    const int wv    = threadIdx.x >> 6;
    const int lane  = threadIdx.x & 63;
    const int eo    = lane >> 1;       // edge within wave (0..31)
    const int h     = lane & 1;        // which 32B half of the 64B rows
    int e = ebase + ((blockIdx.x >> 2) * 4 + wv) * 32 + eo;
    if (e >= 2 * E) return;
    int a, b;
    if (e < E) { a = pos[e];     b = pos[E + e]; }
    else       { a = neg[e - E]; b = neg[e];     }   // neg row1 at E + (e-E) = e
    const __half* ra = zs + ((size_t)slice * n + a) * 32 + h * 16;
    const __half* rb = zs + ((size_t)slice * n + b) * 32 + h * 16;
    union U { float4 f; f16x2 d[4]; };
    U a0, a1, b0, b1;
    a0.f = *(const float4*)&ra[0];
    a1.f = *(const float4*)&ra[8];
    b0.f = *(const float4*)&rb[0];
    b1.f = *(const float4*)&rb[8];
    float p = 0.f;
#if __has_builtin(__builtin_amdgcn_fdot2)
#pragma unroll
    for (int k = 0; k < 4; ++k) p = __builtin_amdgcn_fdot2(a0.d[k], b0.d[k], p, false);
#pragma unroll
    for (int k = 0; k < 4; ++k) p = __builtin_amdgcn_fdot2(a1.d[k], b1.d[k], p, false);
#else
#pragma unroll
    for (int k = 0; k < 4; ++k) {
        p += (float)a0.d[k][0] * (float)b0.d[k][0] + (float)a0.d[k][1] * (float)b0.d[k][1];
        p += (float)a1.d[k][0] * (float)b1.d[k][0] + (float)a1.d[k][1] * (float)b1.d[k][1];
    }
#endif
    p += __shfl_xor(p, 1);
    if (h == 0)
        __builtin_nontemporal_store(p, &psum[(size_t)slice * 2 * E + e]);
}

// ---------------- final sum over 4 slices ----------------
__global__ void k_dsum(const float* __restrict__ psum, float* __restrict__ out, int n2e) {
    int e = blockIdx.x * blockDim.x + threadIdx.x;
    if (e < n2e) {
        float p0 = __builtin_nontemporal_load(&psum[e]);
        float p1 = __builtin_nontemporal_load(&psum[(size_t)n2e + e]);
        float p2 = __builtin_nontemporal_load(&psum[2 * (size_t)n2e + e]);
        float p3 = __builtin_nontemporal_load(&psum[3 * (size_t)n2e + e]);
        out[e] = (p0 + p1) + (p2 + p3);
    }
}

extern "C" void kernel_launch(void* const* d_in, const int* in_sizes, int n_in,
                              void* d_out, int out_size, void* d_ws, size_t ws_size,
                              hipStream_t stream) {
    const float* x   = (const float*)d_in[0];
    const int*   tei = (const int*)d_in[1];
    const int*   pos = (const int*)d_in[2];
    const int*   neg = (const int*)d_in[3];
    const float* W1  = (const float*)d_in[4];
    const float* b1  = (const float*)d_in[5];
    const float* W2  = (const float*)d_in[6];
    const float* b2  = (const float*)d_in[7];
    float* out = (float*)d_out;

    const int N = in_sizes[0] / NFEAT;    // 50000
    const int E = in_sizes[1] / 2;        // 800000
    const int NB = (N + 1023) / 1024;     // scan blocks (49)

    char* ws = (char*)d_ws;
    size_t off = 0;
    __half* g1s = (__half*)(ws + off);                 // [8][N][32] f16 (25.6MB)
    __half* g2s = (__half*)(ws + off);                 // [4][N][32] f16 (g1s dead)
    __half* zs  = (__half*)(ws + off + (size_t)N * OUTF * 2);   // [4][N][32] f16
    off += (size_t)N * HID * 2;
    __half* h1s  = (__half*)(ws + off);                // [8][N][32] f16 (25.6MB)
    float*  psum = (float*)(ws + off);                 // [4][2E] f32 (h1s dead after gemm2)
    off += (size_t)N * HID * 2;
    float*  dinv = (float*)(ws + off);  off += (size_t)N * 4;
    int* rowptr = (int*)(ws + off);     off += (size_t)(N + 1) * 4;
    int* cursor = (int*)(ws + off);     off += (size_t)N * 4;
    int* eidx   = (int*)(ws + off);     off += (size_t)E * 4;
    __half* W1t = (__half*)(ws + off);  off += (size_t)NFEAT * HID * 2;
    __half* W2t = (__half*)(ws + off);  off += (size_t)HID * OUTF * 2;
    int* excl   = (int*)(ws + off);     off += (size_t)N * 4;
    int* bsum   = (int*)(ws + off);     off += (size_t)(NB + 1) * 4;

    // 0) fused prep: W transposes + deg init
    {
        int nbi = (N + 255) / 256;
        k_prep<<<64 + 32 + nbi, 256, 0, stream>>>(W1, W1t, W2, W2t, dinv, N);
    }

    // 1) degree -> parallel scan (scan2 fused into scan3) -> CSR fill
    k_count_deg<<<(E + 255) / 256, 256, 0, stream>>>(tei, dinv, E);
    k_scan1<<<NB, 1024, 0, stream>>>(dinv, excl, bsum, N);
    k_scan3<<<(N + 256) / 256, 256, 0, stream>>>(dinv, excl, bsum, rowptr, cursor, N, NB);
    k_fill<<<(E + 255) / 256, 256, 0, stream>>>(tei, cursor, eidx, E);

    // 2) layer 1: g1s = (f16 sliced) dinv*(x@W1); h1s = relu(dinv*(agg+self)+b1)
    {
        dim3 grid((N + 127) / 128, HID / 128);
        k_gemm_mfma<4, true, false, 5><<<grid, 256, 0, stream>>>(x, W1t, dinv, g1s, N, NFEAT, HID);
        int nblk = 8 * ((N + 3) / 4);
        k_aggs<8, true><<<nblk, 256, 0, stream>>>(rowptr, eidx, g1s, dinv, b1, h1s, N);
    }

    // 3) layer 2: g2s = (f16 sliced) dinv*(h1s@W2); zs = dinv*(agg+self)+b2
    {
        dim3 grid((N + 63) / 64, OUTF / 128);
        k_gemm_mfma<2, false, true, 5><<<grid, 256, 0, stream>>>(h1s, W2t, dinv, g2s, N, HID, OUTF);
        int nblk = 4 * ((N + 3) / 4);
        k_aggs<4, false><<<nblk, 256, 0, stream>>>(rowptr, eidx, g2s, dinv, b2, zs, N);
    }

    // 4) decode: sliced partial dots (pos half, neg half) + final sum
    {
        int nblk = 4 * ((E + 127) / 128);   // per half: 4 waves x 32 edges/block
        k_decode<<<nblk, 256, 0, stream>>>(pos, neg, zs, psum, E, N, 0);
        k_decode<<<nblk, 256, 0, stream>>>(pos, neg, zs, psum, E, N, E);
        k_dsum<<<(2 * E + 255) / 256, 256, 0, stream>>>(psum, out, 2 * E);
    }
}

// Round 7
// 403.275 us; speedup vs baseline: 1.2566x; 1.2566x over previous
//
#include <hip/hip_runtime.h>
#include <hip/hip_fp16.h>

// GCN link-prediction forward. CSR aggregation, row-major fp16 gather tables
// for the aggregates (R5-verified form; R6's sliced aggregates were 2.3x
// slower — VALU-bound on per-wave reduce overhead); XCD-sliced L2-resident z
// for decode (zs[4][N][32], slice = blockIdx&3), R0 TA-floor form split into
// pos/neg launches (diagnostic unmasking of next hotspot); psum + nontemporal
// + dsum (atomics slower, R4); fused prep; scan2 folded into scan3.
// Inputs: x[N,256] f32, train_edges[2,E] i32, pos[2,E] i32, neg[2,E] i32,
//         W1[256,256], b1[256], W2[256,128], b2[128]  (all f32)
// Output: logits[2E] f32.

#define NFEAT 256
#define HID   256
#define OUTF  128

typedef _Float16 f16x8 __attribute__((ext_vector_type(8)));
typedef _Float16 f16x2 __attribute__((ext_vector_type(2)));
typedef float    f32x4 __attribute__((ext_vector_type(4)));

// ---------------- W transpose tile body: Wt[m][k] = (half)W[k][m] ------------
__device__ __forceinline__ void wt_body(const float* __restrict__ W,
                                        __half* __restrict__ Wt,
                                        int K, int M, int bxx, int byy) {
    __shared__ float tile[32][33];
    int k0 = bxx * 32, m0 = byy * 32;
    int tx = threadIdx.x & 31, ty = threadIdx.x >> 5;  // ty 0..7
#pragma unroll
    for (int r = 0; r < 4; ++r)
        tile[ty + r * 8][tx] = W[(size_t)(k0 + ty + r * 8) * M + m0 + tx];
    __syncthreads();
#pragma unroll
    for (int r = 0; r < 4; ++r)
        Wt[(size_t)(m0 + ty + r * 8) * K + k0 + tx] = __float2half(tile[tx][ty + r * 8]);
}

// ---------------- fused prep: wt(W1) | wt(W2) | deg=1 ----------------
__global__ __launch_bounds__(256) void k_prep(
        const float* __restrict__ W1, __half* __restrict__ W1t,
        const float* __restrict__ W2, __half* __restrict__ W2t,
        float* __restrict__ deg, int n) {
    int bid = blockIdx.x;
    if (bid < 64) { wt_body(W1, W1t, NFEAT, HID, bid & 7, bid >> 3); return; }
    bid -= 64;
    if (bid < 32) { wt_body(W2, W2t, HID, OUTF, bid & 7, bid >> 3); return; }
    bid -= 32;
    int i = bid * 256 + threadIdx.x;
    if (i < n) deg[i] = 1.0f;   // self-loop
}

// ---------------- degree count ----------------
__global__ void k_count_deg(const int* __restrict__ ei, float* __restrict__ deg, int E) {
    int e = blockIdx.x * blockDim.x + threadIdx.x;
    if (e < E) atomicAdd(&deg[ei[E + e]], 1.0f);   // dst row
}

// ---------------- parallel scan, pass 1: per-block exclusive scan ------------
// bsum[b] gets the RAW per-block total (scan of totals happens in k_scan3).
__global__ __launch_bounds__(1024) void k_scan1(
        const float* __restrict__ deg, int* __restrict__ excl,
        int* __restrict__ bsum, int n) {
    __shared__ int swsum[16];
    const int t = threadIdx.x, wave = t >> 6, lane = t & 63;
    const int i = blockIdx.x * 1024 + t;
    int v = (i < n) ? (int)deg[i] - 1 : 0;
    int sc = v;
#pragma unroll
    for (int off = 1; off < 64; off <<= 1) {
        int y = __shfl_up(sc, off);
        if (lane >= off) sc += y;
    }
    if (lane == 63) swsum[wave] = sc;
    __syncthreads();
    if (t < 16) {
        int w = swsum[t];
        int scw = w;
#pragma unroll
        for (int off = 1; off < 16; off <<= 1) {
            int y = __shfl_up(scw, off);
            if (t >= off) scw += y;
        }
        swsum[t] = scw - w;
        if (t == 15) bsum[blockIdx.x] = scw;
    }
    __syncthreads();
    if (i < n) excl[i] = swsum[wave] + (sc - v);
}

// ---------------- pass 2 (fused): rowptr/cursor/dinv; lanes re-scan bsum -----
__global__ __launch_bounds__(256) void k_scan3(
        float* __restrict__ deg_dinv, const int* __restrict__ excl,
        const int* __restrict__ bsum, int* __restrict__ rowptr,
        int* __restrict__ cursor, int n, int nb) {
    __shared__ int pbs[65];
    const int t = threadIdx.x;
    if (t < 64) {
        int v = (t < nb) ? bsum[t] : 0;
        int sc = v;
#pragma unroll
        for (int off = 1; off < 64; off <<= 1) {
            int y = __shfl_up(sc, off);
            if (t >= off) sc += y;
        }
        pbs[t] = sc - v;            // exclusive prefix of block totals
        if (t == 63) pbs[64] = sc;  // grand total
    }
    __syncthreads();
    int i = blockIdx.x * 256 + t;
    if (i < n) {
        int rp = excl[i] + pbs[i >> 10];
        rowptr[i] = rp;
        cursor[i] = rp;
        deg_dinv[i] = rsqrtf(deg_dinv[i]);
    } else if (i == n) {
        rowptr[n] = pbs[64];
    }
}

// ---------------- fill CSR adjacency (src ids grouped by dst) ----------------
__global__ void k_fill(const int* __restrict__ ei, int* __restrict__ cursor,
                       int* __restrict__ eidx, int E) {
    int e = blockIdx.x * blockDim.x + threadIdx.x;
    if (e < E) {
        int s = ei[e];
        int d = ei[E + e];
        int p = atomicAdd(&cursor[d], 1);
        eidx[p] = s;
    }
}

// ---------------- MFMA GEMM: out = (half)(dinv[r] * A @ Wt^T) ----------------
// Block: 256 threads = 4 waves (2x2). Block tile (2*MT*16) x 128, wave (MT*16) x 64.
// A: [n][K] (f32 if AF32 else f16). Wt: [M][K] f16. K % 32 == 0.
// SWL=8 for M=256 / SWL=7 for M=128 give plain row-major output.
template <int MT, bool AF32, int SWL>
__global__ __launch_bounds__(256) void k_gemm_mfma(
        const void* __restrict__ Aptr, const __half* __restrict__ Wt,
        const float* __restrict__ dinv, __half* __restrict__ outp,
        int n, int K, int M) {
    constexpr int BM = 2 * MT * 16;
    __shared__ __half As[BM][40];      // [row][k], +8 pad: 2-way banks (free)
    __shared__ __half Bs[128][40];     // [col][k]
    __shared__ __half Cs[4][16][72];   // per-wave C repack (16B-aligned rows)

    const int t    = threadIdx.x;
    const int wave = t >> 6;
    const int lane = t & 63;
    const int row0 = blockIdx.x * BM;
    const int col0 = blockIdx.y * 128;
    const int wm = wave >> 1, wn = wave & 1;
    const int lr = lane & 15;          // fragment m/n index
    const int kq = lane >> 4;          // k-quad: k = kq*8 + j

    f32x4 acc[MT][4];
#pragma unroll
    for (int i = 0; i < MT; ++i)
#pragma unroll
        for (int j = 0; j < 4; ++j) acc[i][j] = (f32x4){0.f, 0.f, 0.f, 0.f};

    for (int k0 = 0; k0 < K; k0 += 32) {
        // ---- stage A tile: BM rows x 32 k ----
        if (AF32) {
            const float* A = (const float*)Aptr;
#pragma unroll
            for (int it = 0; it < BM * 8 / 256; ++it) {
                int q = t + it * 256;
                int r = q >> 3, c4 = q & 7;       // c4: which 4-float chunk
                int gr = min(row0 + r, n - 1);
                float4 v = *(const float4*)&A[(size_t)gr * K + k0 + c4 * 4];
                __half2* dst = (__half2*)&As[r][c4 * 4];
                dst[0] = __floats2half2_rn(v.x, v.y);
                dst[1] = __floats2half2_rn(v.z, v.w);
            }
        } else {
            const __half* A = (const __half*)Aptr;
#pragma unroll
            for (int it = 0; it < BM * 4 / 256; ++it) {
                int q = t + it * 256;
                int r = q >> 2, c8 = q & 3;       // c8: which 8-half chunk
                int gr = min(row0 + r, n - 1);
                *(float4*)&As[r][c8 * 8] = *(const float4*)&A[(size_t)gr * K + k0 + c8 * 8];
            }
        }
        // ---- stage B tile: 128 cols x 32 k from Wt ----
#pragma unroll
        for (int it = 0; it < 2; ++it) {
            int q = t + it * 256;
            int r = q >> 2, c8 = q & 3;
            *(float4*)&Bs[r][c8 * 8] = *(const float4*)&Wt[(size_t)(col0 + r) * K + k0 + c8 * 8];
        }
        __syncthreads();

        f16x8 b[4];
#pragma unroll
        for (int j = 0; j < 4; ++j)
            b[j] = *(const f16x8*)&Bs[wn * 64 + j * 16 + lr][kq * 8];
#pragma unroll
        for (int i = 0; i < MT; ++i) {
            f16x8 a = *(const f16x8*)&As[wm * MT * 16 + i * 16 + lr][kq * 8];
#pragma unroll
            for (int j = 0; j < 4; ++j)
                acc[i][j] = __builtin_amdgcn_mfma_f32_16x16x32_f16(a, b[j], acc[i][j], 0, 0, 0);
        }
        __syncthreads();
    }

    // ---- epilogue: scale by dinv, f16 convert, repack via LDS, 16-B stores ----
    constexpr int SW = 1 << SWL;
#pragma unroll
    for (int i = 0; i < MT; ++i) {
        int gr0 = row0 + wm * MT * 16 + i * 16;
        float dv[4];
#pragma unroll
        for (int r = 0; r < 4; ++r)
            dv[r] = dinv[min(gr0 + kq * 4 + r, n - 1)];
        __syncthreads();   // protect Cs reuse across i iterations
#pragma unroll
        for (int j = 0; j < 4; ++j)
#pragma unroll
            for (int r = 0; r < 4; ++r)
                Cs[wave][kq * 4 + r][j * 16 + lr] = __float2half(acc[i][j][r] * dv[r]);
        __syncthreads();
        int r1 = lane >> 3, c1 = (lane & 7) * 8;
#pragma unroll
        for (int h = 0; h < 2; ++h) {
            int grow = gr0 + r1 + h * 8;
            if (grow < n) {
                int col = col0 + wn * 64 + c1;    // multiple of 8
                size_t oidx = ((size_t)(col >> SWL) * n + grow) * SW + (col & (SW - 1));
                *(float4*)&outp[oidx] = *(const float4*)&Cs[wave][r1 + h * 8][c1];
            }
        }
    }
}

// ---------------- layer-1 aggregate: wave per node, 2 edges per load ----------
// g1 row-major [n][256] f16 (512B rows). lane = half(row sel) x 32 chunks x 16B.
__global__ __launch_bounds__(256) void k_agg1(
        const int* __restrict__ rowptr, const int* __restrict__ eidx,
        const __half* __restrict__ g, const float* __restrict__ dinv,
        const float* __restrict__ bias, __half* __restrict__ out, int n) {
    const int node = (int)(((size_t)blockIdx.x * blockDim.x + threadIdx.x) >> 6);
    const int lane = threadIdx.x & 63;
    const int half = lane >> 5;        // which of 2 rows this lane reads
    const int fl   = lane & 31;        // 16B chunk within row (8 halves)
    if (node >= n) return;
    const int j0  = rowptr[node];
    const int end = rowptr[node + 1];
    const int last = end - 1;          // only used when end > j0

    union U { float4 f; __half2 h[4]; };
    float acc[8] = {0.f, 0.f, 0.f, 0.f, 0.f, 0.f, 0.f, 0.f};
    {   // self row: half 0 only (avoid double count)
        if (half == 0) {
            U u; u.f = *(const float4*)&g[(size_t)node * HID + fl * 8];
#pragma unroll
            for (int k = 0; k < 4; ++k) {
                float2 v = __half22float2(u.h[k]);
                acc[k * 2] += v.x; acc[k * 2 + 1] += v.y;
            }
        }
    }
    if (j0 < end) {
        int s0 = eidx[min(j0 + half, last)];
        int s1 = eidx[min(j0 + 2 + half, last)];
        for (int j = j0; j < end; j += 4) {
            int p0 = eidx[min(j + 4 + half, last)];   // prefetch next iter's indices
            int p1 = eidx[min(j + 6 + half, last)];
            U u0, u1;
            u0.f = *(const float4*)&g[(size_t)s0 * HID + fl * 8];
            u1.f = *(const float4*)&g[(size_t)s1 * HID + fl * 8];
            if (j + half < end) {
#pragma unroll
                for (int k = 0; k < 4; ++k) {
                    float2 v = __half22float2(u0.h[k]);
                    acc[k * 2] += v.x; acc[k * 2 + 1] += v.y;
                }
            }
            if (j + 2 + half < end) {
#pragma unroll
                for (int k = 0; k < 4; ++k) {
                    float2 v = __half22float2(u1.h[k]);
                    acc[k * 2] += v.x; acc[k * 2 + 1] += v.y;
                }
            }
            s0 = p0; s1 = p1;
        }
    }
    // reduce across the two halves
#pragma unroll
    for (int k = 0; k < 8; ++k) acc[k] += __shfl_xor(acc[k], 32);
    if (half == 0) {
        const float sc = dinv[node];
        const int f0 = fl * 8;
        U r;
#pragma unroll
        for (int k = 0; k < 4; ++k) {
            float2 bb = *(const float2*)&bias[f0 + k * 2];
            r.h[k] = __floats2half2_rn(fmaxf(sc * acc[k * 2]     + bb.x, 0.f),
                                       fmaxf(sc * acc[k * 2 + 1] + bb.y, 0.f));
        }
        *(float4*)&out[(size_t)node * HID + f0] = r.f;
    }
}

// ---------------- layer-2 aggregate: wave per node, 4 edges per load ----------
// g2 row-major [n][128] f16 (256B rows) -> zs [4][n][32] f16 (sliced for decode).
__global__ __launch_bounds__(256) void k_agg2(
        const int* __restrict__ rowptr, const int* __restrict__ eidx,
        const __half* __restrict__ g, const float* __restrict__ dinv,
        const float* __restrict__ bias, __half* __restrict__ zs, int n) {
    const int node = (int)(((size_t)blockIdx.x * blockDim.x + threadIdx.x) >> 6);
    const int lane = threadIdx.x & 63;
    const int q    = lane >> 4;        // which of 4 rows this lane reads
    const int fl   = lane & 15;        // 16B chunk within row
    if (node >= n) return;
    const int j0  = rowptr[node];
    const int end = rowptr[node + 1];
    const int last = end - 1;

    union U { float4 f; __half2 h[4]; };
    float acc[8] = {0.f, 0.f, 0.f, 0.f, 0.f, 0.f, 0.f, 0.f};
    if (q == 0) {   // self row
        U u; u.f = *(const float4*)&g[(size_t)node * OUTF + fl * 8];
#pragma unroll
        for (int k = 0; k < 4; ++k) {
            float2 v = __half22float2(u.h[k]);
            acc[k * 2] += v.x; acc[k * 2 + 1] += v.y;
        }
    }
    if (j0 < end) {
        int s0 = eidx[min(j0 + q, last)];
        for (int j = j0; j < end; j += 4) {
            int p0 = eidx[min(j + 4 + q, last)];
            U u0; u0.f = *(const float4*)&g[(size_t)s0 * OUTF + fl * 8];
            if (j + q < end) {
#pragma unroll
                for (int k = 0; k < 4; ++k) {
                    float2 v = __half22float2(u0.h[k]);
                    acc[k * 2] += v.x; acc[k * 2 + 1] += v.y;
                }
            }
            s0 = p0;
        }
    }
#pragma unroll
    for (int k = 0; k < 8; ++k) {
        acc[k] += __shfl_xor(acc[k], 16);
        acc[k] += __shfl_xor(acc[k], 32);
    }
    if (q == 0) {
        const float sc = dinv[node];
        const int f0 = fl * 8;              // 0,8,...,120
        U r;
#pragma unroll
        for (int k = 0; k < 4; ++k) {
            float2 bb = *(const float2*)&bias[f0 + k * 2];
            r.h[k] = __floats2half2_rn(sc * acc[k * 2]     + bb.x,
                                       sc * acc[k * 2 + 1] + bb.y);
        }
        // slice-major store: slice = f0>>5, 16B chunk stays within slice
        *(float4*)&zs[((size_t)(f0 >> 5) * n + node) * 32 + (f0 & 31)] = r.f;
    }
}

// ---------------- decode (sliced): psum[slice][e], 32 edges/wave -------------
// zs [4][n][32] f16; slice = bx & 3 (XCD-pinned, 3.2MB L2-resident).
// lane = (edge-in-wave)*2 + h; lane loads 32B of BOTH endpoint rows, 16-feat
// dot. ebase splits the launch into pos/neg halves (diagnostic + uniform branch).
__global__ __launch_bounds__(256) void k_decode(
        const int* __restrict__ pos, const int* __restrict__ neg,
        const __half* __restrict__ zs, float* __restrict__ psum,
        int E, int n, int ebase) {
    const int slice = blockIdx.x & 3;
    const int wv    = threadIdx.x >> 6;
    const int lane  = threadIdx.x & 63;
    const int eo    = lane >> 1;       // edge within wave (0..31)
    const int h     = lane & 1;        // which 32B half of the 64B rows
    int e = ebase + ((blockIdx.x >> 2) * 4 + wv) * 32 + eo;
    if (e >= 2 * E) return;
    int a, b;
    if (e < E) { a = pos[e];     b = pos[E + e]; }
    else       { a = neg[e - E]; b = neg[e];     }   // neg row1 at E + (e-E) = e
    const __half* ra = zs + ((size_t)slice * n + a) * 32 + h * 16;
    const __half* rb = zs + ((size_t)slice * n + b) * 32 + h * 16;
    union U { float4 f; f16x2 d[4]; };
    U a0, a1, b0, b1;
    a0.f = *(const float4*)&ra[0];
    a1.f = *(const float4*)&ra[8];
    b0.f = *(const float4*)&rb[0];
    b1.f = *(const float4*)&rb[8];
    float p = 0.f;
#if __has_builtin(__builtin_amdgcn_fdot2)
#pragma unroll
    for (int k = 0; k < 4; ++k) p = __builtin_amdgcn_fdot2(a0.d[k], b0.d[k], p, false);
#pragma unroll
    for (int k = 0; k < 4; ++k) p = __builtin_amdgcn_fdot2(a1.d[k], b1.d[k], p, false);
#else
#pragma unroll
    for (int k = 0; k < 4; ++k) {
        p += (float)a0.d[k][0] * (float)b0.d[k][0] + (float)a0.d[k][1] * (float)b0.d[k][1];
        p += (float)a1.d[k][0] * (float)b1.d[k][0] + (float)a1.d[k][1] * (float)b1.d[k][1];
    }
#endif
    p += __shfl_xor(p, 1);
    if (h == 0)
        __builtin_nontemporal_store(p, &psum[(size_t)slice * 2 * E + e]);
}

// ---------------- final sum over 4 slices ----------------
__global__ void k_dsum(const float* __restrict__ psum, float* __restrict__ out, int n2e) {
    int e = blockIdx.x * blockDim.x + threadIdx.x;
    if (e < n2e) {
        float p0 = __builtin_nontemporal_load(&psum[e]);
        float p1 = __builtin_nontemporal_load(&psum[(size_t)n2e + e]);
        float p2 = __builtin_nontemporal_load(&psum[2 * (size_t)n2e + e]);
        float p3 = __builtin_nontemporal_load(&psum[3 * (size_t)n2e + e]);
        out[e] = (p0 + p1) + (p2 + p3);
    }
}

extern "C" void kernel_launch(void* const* d_in, const int* in_sizes, int n_in,
                              void* d_out, int out_size, void* d_ws, size_t ws_size,
                              hipStream_t stream) {
    const float* x   = (const float*)d_in[0];
    const int*   tei = (const int*)d_in[1];
    const int*   pos = (const int*)d_in[2];
    const int*   neg = (const int*)d_in[3];
    const float* W1  = (const float*)d_in[4];
    const float* b1  = (const float*)d_in[5];
    const float* W2  = (const float*)d_in[6];
    const float* b2  = (const float*)d_in[7];
    float* out = (float*)d_out;

    const int N = in_sizes[0] / NFEAT;    // 50000
    const int E = in_sizes[1] / 2;        // 800000
    const int NB = (N + 1023) / 1024;     // scan blocks (49)

    char* ws = (char*)d_ws;
    size_t off = 0;
    __half* g1h = (__half*)(ws + off);                 // [N][256] f16 (25.6MB)
    __half* g2h = (__half*)(ws + off);                 // [N][128] f16 (g1 dead)
    __half* zs  = (__half*)(ws + off + (size_t)N * OUTF * 2);   // [4][N][32] f16
    off += (size_t)N * HID * 2;
    __half* h1h  = (__half*)(ws + off);                // [N][256] f16 (25.6MB)
    float*  psum = (float*)(ws + off);                 // [4][2E] f32 (h1 dead after gemm2)
    off += (size_t)N * HID * 2;
    float*  dinv = (float*)(ws + off);  off += (size_t)N * 4;
    int* rowptr = (int*)(ws + off);     off += (size_t)(N + 1) * 4;
    int* cursor = (int*)(ws + off);     off += (size_t)N * 4;
    int* eidx   = (int*)(ws + off);     off += (size_t)E * 4;
    __half* W1t = (__half*)(ws + off);  off += (size_t)NFEAT * HID * 2;
    __half* W2t = (__half*)(ws + off);  off += (size_t)HID * OUTF * 2;
    int* excl   = (int*)(ws + off);     off += (size_t)N * 4;
    int* bsum   = (int*)(ws + off);     off += (size_t)(NB + 1) * 4;

    // 0) fused prep: W transposes + deg init
    {
        int nbi = (N + 255) / 256;
        k_prep<<<64 + 32 + nbi, 256, 0, stream>>>(W1, W1t, W2, W2t, dinv, N);
    }

    // 1) degree -> parallel scan (scan2 fused into scan3) -> CSR fill
    k_count_deg<<<(E + 255) / 256, 256, 0, stream>>>(tei, dinv, E);
    k_scan1<<<NB, 1024, 0, stream>>>(dinv, excl, bsum, N);
    k_scan3<<<(N + 256) / 256, 256, 0, stream>>>(dinv, excl, bsum, rowptr, cursor, N, NB);
    k_fill<<<(E + 255) / 256, 256, 0, stream>>>(tei, cursor, eidx, E);

    // 2) layer 1: g1 = (f16) dinv*(x@W1); h1 = (f16) relu(dinv*(agg+self)+b1)
    {
        dim3 grid((N + 127) / 128, HID / 128);
        k_gemm_mfma<4, true, 8><<<grid, 256, 0, stream>>>(x, W1t, dinv, g1h, N, NFEAT, HID);
        int nblk = (int)(((size_t)N * 64 + 255) / 256);
        k_agg1<<<nblk, 256, 0, stream>>>(rowptr, eidx, g1h, dinv, b1, h1h, N);
    }

    // 3) layer 2: g2 = (f16) dinv*(h1@W2); zs = (f16, [4][N][32]) dinv*(agg+self)+b2
    {
        dim3 grid((N + 63) / 64, OUTF / 128);
        k_gemm_mfma<2, false, 7><<<grid, 256, 0, stream>>>(h1h, W2t, dinv, g2h, N, HID, OUTF);
        int nblk = (int)(((size_t)N * 64 + 255) / 256);
        k_agg2<<<nblk, 256, 0, stream>>>(rowptr, eidx, g2h, dinv, b2, zs, N);
    }

    // 4) decode: sliced partial dots (pos half, neg half) + final sum
    {
        int nblk = 4 * ((E + 127) / 128);   // per half: 4 waves x 32 edges/block
        k_decode<<<nblk, 256, 0, stream>>>(pos, neg, zs, psum, E, N, 0);
        k_decode<<<nblk, 256, 0, stream>>>(pos, neg, zs, psum, E, N, E);
        k_dsum<<<(2 * E + 255) / 256, 256, 0, stream>>>(psum, out, 2 * E);
    }
}

// Round 8
// 401.124 us; speedup vs baseline: 1.2634x; 1.0054x over previous
//
#include <hip/hip_runtime.h>
#include <hip/hip_fp16.h>

// GCN link-prediction forward. CSR aggregation, row-major fp16 gather tables
// for the aggregates; XCD-sliced L2-resident z for decode (zs[4][N][32]),
// R0 TA-floor decode split into pos/neg launches; psum + nontemporal + dsum;
// fused prep; scan2 folded into scan3. NEW (R8): k_fill/k_count_deg batch 4
// edges/thread (4 concurrent atomics, ILP latency hiding) and k_fill uses
// nontemporal eidx stores (kills 64B dirty-line write amplification, was
// 52.8MB writes for 3.2MB data).
// Inputs: x[N,256] f32, train_edges[2,E] i32, pos[2,E] i32, neg[2,E] i32,
//         W1[256,256], b1[256], W2[256,128], b2[128]  (all f32)
// Output: logits[2E] f32.

#define NFEAT 256
#define HID   256
#define OUTF  128
#define FPE   4     // edges per thread in fill/count

typedef _Float16 f16x8 __attribute__((ext_vector_type(8)));
typedef _Float16 f16x2 __attribute__((ext_vector_type(2)));
typedef float    f32x4 __attribute__((ext_vector_type(4)));

// ---------------- W transpose tile body: Wt[m][k] = (half)W[k][m] ------------
__device__ __forceinline__ void wt_body(const float* __restrict__ W,
                                        __half* __restrict__ Wt,
                                        int K, int M, int bxx, int byy) {
    __shared__ float tile[32][33];
    int k0 = bxx * 32, m0 = byy * 32;
    int tx = threadIdx.x & 31, ty = threadIdx.x >> 5;  // ty 0..7
#pragma unroll
    for (int r = 0; r < 4; ++r)
        tile[ty + r * 8][tx] = W[(size_t)(k0 + ty + r * 8) * M + m0 + tx];
    __syncthreads();
#pragma unroll
    for (int r = 0; r < 4; ++r)
        Wt[(size_t)(m0 + ty + r * 8) * K + k0 + tx] = __float2half(tile[tx][ty + r * 8]);
}

// ---------------- fused prep: wt(W1) | wt(W2) | deg=1 ----------------
__global__ __launch_bounds__(256) void k_prep(
        const float* __restrict__ W1, __half* __restrict__ W1t,
        const float* __restrict__ W2, __half* __restrict__ W2t,
        float* __restrict__ deg, int n) {
    int bid = blockIdx.x;
    if (bid < 64) { wt_body(W1, W1t, NFEAT, HID, bid & 7, bid >> 3); return; }
    bid -= 64;
    if (bid < 32) { wt_body(W2, W2t, HID, OUTF, bid & 7, bid >> 3); return; }
    bid -= 32;
    int i = bid * 256 + threadIdx.x;
    if (i < n) deg[i] = 1.0f;   // self-loop
}

// ---------------- degree count: 4 edges/thread, fire-and-forget atomics ------
__global__ __launch_bounds__(256) void k_count_deg(
        const int* __restrict__ ei, float* __restrict__ deg, int E, int stride) {
    const int t = blockIdx.x * 256 + threadIdx.x;
    int d[FPE];
#pragma unroll
    for (int k = 0; k < FPE; ++k) {
        int e = t + k * stride;
        if (e < E) d[k] = ei[E + e];
    }
#pragma unroll
    for (int k = 0; k < FPE; ++k) {
        int e = t + k * stride;
        if (e < E) atomicAdd(&deg[d[k]], 1.0f);
    }
}

// ---------------- parallel scan, pass 1: per-block exclusive scan ------------
// bsum[b] gets the RAW per-block total (scan of totals happens in k_scan3).
__global__ __launch_bounds__(1024) void k_scan1(
        const float* __restrict__ deg, int* __restrict__ excl,
        int* __restrict__ bsum, int n) {
    __shared__ int swsum[16];
    const int t = threadIdx.x, wave = t >> 6, lane = t & 63;
    const int i = blockIdx.x * 1024 + t;
    int v = (i < n) ? (int)deg[i] - 1 : 0;
    int sc = v;
#pragma unroll
    for (int off = 1; off < 64; off <<= 1) {
        int y = __shfl_up(sc, off);
        if (lane >= off) sc += y;
    }
    if (lane == 63) swsum[wave] = sc;
    __syncthreads();
    if (t < 16) {
        int w = swsum[t];
        int scw = w;
#pragma unroll
        for (int off = 1; off < 16; off <<= 1) {
            int y = __shfl_up(scw, off);
            if (t >= off) scw += y;
        }
        swsum[t] = scw - w;
        if (t == 15) bsum[blockIdx.x] = scw;
    }
    __syncthreads();
    if (i < n) excl[i] = swsum[wave] + (sc - v);
}

// ---------------- pass 2 (fused): rowptr/cursor/dinv; lanes re-scan bsum -----
__global__ __launch_bounds__(256) void k_scan3(
        float* __restrict__ deg_dinv, const int* __restrict__ excl,
        const int* __restrict__ bsum, int* __restrict__ rowptr,
        int* __restrict__ cursor, int n, int nb) {
    __shared__ int pbs[65];
    const int t = threadIdx.x;
    if (t < 64) {
        int v = (t < nb) ? bsum[t] : 0;
        int sc = v;
#pragma unroll
        for (int off = 1; off < 64; off <<= 1) {
            int y = __shfl_up(sc, off);
            if (t >= off) sc += y;
        }
        pbs[t] = sc - v;            // exclusive prefix of block totals
        if (t == 63) pbs[64] = sc;  // grand total
    }
    __syncthreads();
    int i = blockIdx.x * 256 + t;
    if (i < n) {
        int rp = excl[i] + pbs[i >> 10];
        rowptr[i] = rp;
        cursor[i] = rp;
        deg_dinv[i] = rsqrtf(deg_dinv[i]);
    } else if (i == n) {
        rowptr[n] = pbs[64];
    }
}

// ---------------- fill CSR adjacency: 4 edges/thread, NT scattered stores ----
__global__ __launch_bounds__(256) void k_fill(
        const int* __restrict__ ei, int* __restrict__ cursor,
        int* __restrict__ eidx, int E, int stride) {
    const int t = blockIdx.x * 256 + threadIdx.x;
    int s[FPE], d[FPE], p[FPE];
#pragma unroll
    for (int k = 0; k < FPE; ++k) {
        int e = t + k * stride;
        if (e < E) { s[k] = ei[e]; d[k] = ei[E + e]; }
    }
#pragma unroll
    for (int k = 0; k < FPE; ++k) {
        int e = t + k * stride;
        if (e < E) p[k] = atomicAdd(&cursor[d[k]], 1);
    }
#pragma unroll
    for (int k = 0; k < FPE; ++k) {
        int e = t + k * stride;
        if (e < E) __builtin_nontemporal_store(s[k], &eidx[p[k]]);
    }
}

// ---------------- MFMA GEMM: out = (half)(dinv[r] * A @ Wt^T) ----------------
// Block: 256 threads = 4 waves (2x2). Block tile (2*MT*16) x 128, wave (MT*16) x 64.
// A: [n][K] (f32 if AF32 else f16). Wt: [M][K] f16. K % 32 == 0.
// SWL=8 for M=256 / SWL=7 for M=128 give plain row-major output.
template <int MT, bool AF32, int SWL>
__global__ __launch_bounds__(256) void k_gemm_mfma(
        const void* __restrict__ Aptr, const __half* __restrict__ Wt,
        const float* __restrict__ dinv, __half* __restrict__ outp,
        int n, int K, int M) {
    constexpr int BM = 2 * MT * 16;
    __shared__ __half As[BM][40];      // [row][k], +8 pad: 2-way banks (free)
    __shared__ __half Bs[128][40];     // [col][k]
    __shared__ __half Cs[4][16][72];   // per-wave C repack (16B-aligned rows)

    const int t    = threadIdx.x;
    const int wave = t >> 6;
    const int lane = t & 63;
    const int row0 = blockIdx.x * BM;
    const int col0 = blockIdx.y * 128;
    const int wm = wave >> 1, wn = wave & 1;
    const int lr = lane & 15;          // fragment m/n index
    const int kq = lane >> 4;          // k-quad: k = kq*8 + j

    f32x4 acc[MT][4];
#pragma unroll
    for (int i = 0; i < MT; ++i)
#pragma unroll
        for (int j = 0; j < 4; ++j) acc[i][j] = (f32x4){0.f, 0.f, 0.f, 0.f};

    for (int k0 = 0; k0 < K; k0 += 32) {
        // ---- stage A tile: BM rows x 32 k ----
        if (AF32) {
            const float* A = (const float*)Aptr;
#pragma unroll
            for (int it = 0; it < BM * 8 / 256; ++it) {
                int q = t + it * 256;
                int r = q >> 3, c4 = q & 7;       // c4: which 4-float chunk
                int gr = min(row0 + r, n - 1);
                float4 v = *(const float4*)&A[(size_t)gr * K + k0 + c4 * 4];
                __half2* dst = (__half2*)&As[r][c4 * 4];
                dst[0] = __floats2half2_rn(v.x, v.y);
                dst[1] = __floats2half2_rn(v.z, v.w);
            }
        } else {
            const __half* A = (const __half*)Aptr;
#pragma unroll
            for (int it = 0; it < BM * 4 / 256; ++it) {
                int q = t + it * 256;
                int r = q >> 2, c8 = q & 3;       // c8: which 8-half chunk
                int gr = min(row0 + r, n - 1);
                *(float4*)&As[r][c8 * 8] = *(const float4*)&A[(size_t)gr * K + k0 + c8 * 8];
            }
        }
        // ---- stage B tile: 128 cols x 32 k from Wt ----
#pragma unroll
        for (int it = 0; it < 2; ++it) {
            int q = t + it * 256;
            int r = q >> 2, c8 = q & 3;
            *(float4*)&Bs[r][c8 * 8] = *(const float4*)&Wt[(size_t)(col0 + r) * K + k0 + c8 * 8];
        }
        __syncthreads();

        f16x8 b[4];
#pragma unroll
        for (int j = 0; j < 4; ++j)
            b[j] = *(const f16x8*)&Bs[wn * 64 + j * 16 + lr][kq * 8];
#pragma unroll
        for (int i = 0; i < MT; ++i) {
            f16x8 a = *(const f16x8*)&As[wm * MT * 16 + i * 16 + lr][kq * 8];
#pragma unroll
            for (int j = 0; j < 4; ++j)
                acc[i][j] = __builtin_amdgcn_mfma_f32_16x16x32_f16(a, b[j], acc[i][j], 0, 0, 0);
        }
        __syncthreads();
    }

    // ---- epilogue: scale by dinv, f16 convert, repack via LDS, 16-B stores ----
    constexpr int SW = 1 << SWL;
#pragma unroll
    for (int i = 0; i < MT; ++i) {
        int gr0 = row0 + wm * MT * 16 + i * 16;
        float dv[4];
#pragma unroll
        for (int r = 0; r < 4; ++r)
            dv[r] = dinv[min(gr0 + kq * 4 + r, n - 1)];
        __syncthreads();   // protect Cs reuse across i iterations
#pragma unroll
        for (int j = 0; j < 4; ++j)
#pragma unroll
            for (int r = 0; r < 4; ++r)
                Cs[wave][kq * 4 + r][j * 16 + lr] = __float2half(acc[i][j][r] * dv[r]);
        __syncthreads();
        int r1 = lane >> 3, c1 = (lane & 7) * 8;
#pragma unroll
        for (int h = 0; h < 2; ++h) {
            int grow = gr0 + r1 + h * 8;
            if (grow < n) {
                int col = col0 + wn * 64 + c1;    // multiple of 8
                size_t oidx = ((size_t)(col >> SWL) * n + grow) * SW + (col & (SW - 1));
                *(float4*)&outp[oidx] = *(const float4*)&Cs[wave][r1 + h * 8][c1];
            }
        }
    }
}

// ---------------- layer-1 aggregate: wave per node, 2 edges per load ----------
// g1 row-major [n][256] f16 (512B rows). lane = half(row sel) x 32 chunks x 16B.
__global__ __launch_bounds__(256) void k_agg1(
        const int* __restrict__ rowptr, const int* __restrict__ eidx,
        const __half* __restrict__ g, const float* __restrict__ dinv,
        const float* __restrict__ bias, __half* __restrict__ out, int n) {
    const int node = (int)(((size_t)blockIdx.x * blockDim.x + threadIdx.x) >> 6);
    const int lane = threadIdx.x & 63;
    const int half = lane >> 5;        // which of 2 rows this lane reads
    const int fl   = lane & 31;        // 16B chunk within row (8 halves)
    if (node >= n) return;
    const int j0  = rowptr[node];
    const int end = rowptr[node + 1];
    const int last = end - 1;          // only used when end > j0

    union U { float4 f; __half2 h[4]; };
    float acc[8] = {0.f, 0.f, 0.f, 0.f, 0.f, 0.f, 0.f, 0.f};
    {   // self row: half 0 only (avoid double count)
        if (half == 0) {
            U u; u.f = *(const float4*)&g[(size_t)node * HID + fl * 8];
#pragma unroll
            for (int k = 0; k < 4; ++k) {
                float2 v = __half22float2(u.h[k]);
                acc[k * 2] += v.x; acc[k * 2 + 1] += v.y;
            }
        }
    }
    if (j0 < end) {
        int s0 = eidx[min(j0 + half, last)];
        int s1 = eidx[min(j0 + 2 + half, last)];
        for (int j = j0; j < end; j += 4) {
            int p0 = eidx[min(j + 4 + half, last)];   // prefetch next iter's indices
            int p1 = eidx[min(j + 6 + half, last)];
            U u0, u1;
            u0.f = *(const float4*)&g[(size_t)s0 * HID + fl * 8];
            u1.f = *(const float4*)&g[(size_t)s1 * HID + fl * 8];
            if (j + half < end) {
#pragma unroll
                for (int k = 0; k < 4; ++k) {
                    float2 v = __half22float2(u0.h[k]);
                    acc[k * 2] += v.x; acc[k * 2 + 1] += v.y;
                }
            }
            if (j + 2 + half < end) {
#pragma unroll
                for (int k = 0; k < 4; ++k) {
                    float2 v = __half22float2(u1.h[k]);
                    acc[k * 2] += v.x; acc[k * 2 + 1] += v.y;
                }
            }
            s0 = p0; s1 = p1;
        }
    }
    // reduce across the two halves
#pragma unroll
    for (int k = 0; k < 8; ++k) acc[k] += __shfl_xor(acc[k], 32);
    if (half == 0) {
        const float sc = dinv[node];
        const int f0 = fl * 8;
        U r;
#pragma unroll
        for (int k = 0; k < 4; ++k) {
            float2 bb = *(const float2*)&bias[f0 + k * 2];
            r.h[k] = __floats2half2_rn(fmaxf(sc * acc[k * 2]     + bb.x, 0.f),
                                       fmaxf(sc * acc[k * 2 + 1] + bb.y, 0.f));
        }
        *(float4*)&out[(size_t)node * HID + f0] = r.f;
    }
}

// ---------------- layer-2 aggregate: wave per node, 4 edges per load ----------
// g2 row-major [n][128] f16 (256B rows) -> zs [4][n][32] f16 (sliced for decode).
__global__ __launch_bounds__(256) void k_agg2(
        const int* __restrict__ rowptr, const int* __restrict__ eidx,
        const __half* __restrict__ g, const float* __restrict__ dinv,
        const float* __restrict__ bias, __half* __restrict__ zs, int n) {
    const int node = (int)(((size_t)blockIdx.x * blockDim.x + threadIdx.x) >> 6);
    const int lane = threadIdx.x & 63;
    const int q    = lane >> 4;        // which of 4 rows this lane reads
    const int fl   = lane & 15;        // 16B chunk within row
    if (node >= n) return;
    const int j0  = rowptr[node];
    const int end = rowptr[node + 1];
    const int last = end - 1;

    union U { float4 f; __half2 h[4]; };
    float acc[8] = {0.f, 0.f, 0.f, 0.f, 0.f, 0.f, 0.f, 0.f};
    if (q == 0) {   // self row
        U u; u.f = *(const float4*)&g[(size_t)node * OUTF + fl * 8];
#pragma unroll
        for (int k = 0; k < 4; ++k) {
            float2 v = __half22float2(u.h[k]);
            acc[k * 2] += v.x; acc[k * 2 + 1] += v.y;
        }
    }
    if (j0 < end) {
        int s0 = eidx[min(j0 + q, last)];
        for (int j = j0; j < end; j += 4) {
            int p0 = eidx[min(j + 4 + q, last)];
            U u0; u0.f = *(const float4*)&g[(size_t)s0 * OUTF + fl * 8];
            if (j + q < end) {
#pragma unroll
                for (int k = 0; k < 4; ++k) {
                    float2 v = __half22float2(u0.h[k]);
                    acc[k * 2] += v.x; acc[k * 2 + 1] += v.y;
                }
            }
            s0 = p0;
        }
    }
#pragma unroll
    for (int k = 0; k < 8; ++k) {
        acc[k] += __shfl_xor(acc[k], 16);
        acc[k] += __shfl_xor(acc[k], 32);
    }
    if (q == 0) {
        const float sc = dinv[node];
        const int f0 = fl * 8;              // 0,8,...,120
        U r;
#pragma unroll
        for (int k = 0; k < 4; ++k) {
            float2 bb = *(const float2*)&bias[f0 + k * 2];
            r.h[k] = __floats2half2_rn(sc * acc[k * 2]     + bb.x,
                                       sc * acc[k * 2 + 1] + bb.y);
        }
        // slice-major store: slice = f0>>5, 16B chunk stays within slice
        *(float4*)&zs[((size_t)(f0 >> 5) * n + node) * 32 + (f0 & 31)] = r.f;
    }
}

// ---------------- decode (sliced): psum[slice][e], 32 edges/wave -------------
// zs [4][n][32] f16; slice = bx & 3 (XCD-pinned, 3.2MB L2-resident).
// lane = (edge-in-wave)*2 + h; lane loads 32B of BOTH endpoint rows, 16-feat
// dot. ebase splits the launch into pos/neg halves (diagnostic + uniform branch).
__global__ __launch_bounds__(256) void k_decode(
        const int* __restrict__ pos, const int* __restrict__ neg,
        const __half* __restrict__ zs, float* __restrict__ psum,
        int E, int n, int ebase) {
    const int slice = blockIdx.x & 3;
    const int wv    = threadIdx.x >> 6;
    const int lane  = threadIdx.x & 63;
    const int eo    = lane >> 1;       // edge within wave (0..31)
    const int h     = lane & 1;        // which 32B half of the 64B rows
    int e = ebase + ((blockIdx.x >> 2) * 4 + wv) * 32 + eo;
    if (e >= 2 * E) return;
    int a, b;
    if (e < E) { a = pos[e];     b = pos[E + e]; }
    else       { a = neg[e - E]; b = neg[e];     }   // neg row1 at E + (e-E) = e
    const __half* ra = zs + ((size_t)slice * n + a) * 32 + h * 16;
    const __half* rb = zs + ((size_t)slice * n + b) * 32 + h * 16;
    union U { float4 f; f16x2 d[4]; };
    U a0, a1, b0, b1;
    a0.f = *(const float4*)&ra[0];
    a1.f = *(const float4*)&ra[8];
    b0.f = *(const float4*)&rb[0];
    b1.f = *(const float4*)&rb[8];
    float p = 0.f;
#if __has_builtin(__builtin_amdgcn_fdot2)
#pragma unroll
    for (int k = 0; k < 4; ++k) p = __builtin_amdgcn_fdot2(a0.d[k], b0.d[k], p, false);
#pragma unroll
    for (int k = 0; k < 4; ++k) p = __builtin_amdgcn_fdot2(a1.d[k], b1.d[k], p, false);
#else
#pragma unroll
    for (int k = 0; k < 4; ++k) {
        p += (float)a0.d[k][0] * (float)b0.d[k][0] + (float)a0.d[k][1] * (float)b0.d[k][1];
        p += (float)a1.d[k][0] * (float)b1.d[k][0] + (float)a1.d[k][1] * (float)b1.d[k][1];
    }
#endif
    p += __shfl_xor(p, 1);
    if (h == 0)
        __builtin_nontemporal_store(p, &psum[(size_t)slice * 2 * E + e]);
}

// ---------------- final sum over 4 slices ----------------
__global__ void k_dsum(const float* __restrict__ psum, float* __restrict__ out, int n2e) {
    int e = blockIdx.x * blockDim.x + threadIdx.x;
    if (e < n2e) {
        float p0 = __builtin_nontemporal_load(&psum[e]);
        float p1 = __builtin_nontemporal_load(&psum[(size_t)n2e + e]);
        float p2 = __builtin_nontemporal_load(&psum[2 * (size_t)n2e + e]);
        float p3 = __builtin_nontemporal_load(&psum[3 * (size_t)n2e + e]);
        out[e] = (p0 + p1) + (p2 + p3);
    }
}

extern "C" void kernel_launch(void* const* d_in, const int* in_sizes, int n_in,
                              void* d_out, int out_size, void* d_ws, size_t ws_size,
                              hipStream_t stream) {
    const float* x   = (const float*)d_in[0];
    const int*   tei = (const int*)d_in[1];
    const int*   pos = (const int*)d_in[2];
    const int*   neg = (const int*)d_in[3];
    const float* W1  = (const float*)d_in[4];
    const float* b1  = (const float*)d_in[5];
    const float* W2  = (const float*)d_in[6];
    const float* b2  = (const float*)d_in[7];
    float* out = (float*)d_out;

    const int N = in_sizes[0] / NFEAT;    // 50000
    const int E = in_sizes[1] / 2;        // 800000
    const int NB = (N + 1023) / 1024;     // scan blocks (49)

    char* ws = (char*)d_ws;
    size_t off = 0;
    __half* g1h = (__half*)(ws + off);                 // [N][256] f16 (25.6MB)
    __half* g2h = (__half*)(ws + off);                 // [N][128] f16 (g1 dead)
    __half* zs  = (__half*)(ws + off + (size_t)N * OUTF * 2);   // [4][N][32] f16
    off += (size_t)N * HID * 2;
    __half* h1h  = (__half*)(ws + off);                // [N][256] f16 (25.6MB)
    float*  psum = (float*)(ws + off);                 // [4][2E] f32 (h1 dead after gemm2)
    off += (size_t)N * HID * 2;
    float*  dinv = (float*)(ws + off);  off += (size_t)N * 4;
    int* rowptr = (int*)(ws + off);     off += (size_t)(N + 1) * 4;
    int* cursor = (int*)(ws + off);     off += (size_t)N * 4;
    int* eidx   = (int*)(ws + off);     off += (size_t)E * 4;
    __half* W1t = (__half*)(ws + off);  off += (size_t)NFEAT * HID * 2;
    __half* W2t = (__half*)(ws + off);  off += (size_t)HID * OUTF * 2;
    int* excl   = (int*)(ws + off);     off += (size_t)N * 4;
    int* bsum   = (int*)(ws + off);     off += (size_t)(NB + 1) * 4;

    // 0) fused prep: W transposes + deg init
    {
        int nbi = (N + 255) / 256;
        k_prep<<<64 + 32 + nbi, 256, 0, stream>>>(W1, W1t, W2, W2t, dinv, N);
    }

    // 1) degree -> parallel scan (scan2 fused into scan3) -> CSR fill
    {
        int nblk = (E + 256 * FPE - 1) / (256 * FPE);
        int stride = nblk * 256;
        k_count_deg<<<nblk, 256, 0, stream>>>(tei, dinv, E, stride);
        k_scan1<<<NB, 1024, 0, stream>>>(dinv, excl, bsum, N);
        k_scan3<<<(N + 256) / 256, 256, 0, stream>>>(dinv, excl, bsum, rowptr, cursor, N, NB);
        k_fill<<<nblk, 256, 0, stream>>>(tei, cursor, eidx, E, stride);
    }

    // 2) layer 1: g1 = (f16) dinv*(x@W1); h1 = (f16) relu(dinv*(agg+self)+b1)
    {
        dim3 grid((N + 127) / 128, HID / 128);
        k_gemm_mfma<4, true, 8><<<grid, 256, 0, stream>>>(x, W1t, dinv, g1h, N, NFEAT, HID);
        int nblk = (int)(((size_t)N * 64 + 255) / 256);
        k_agg1<<<nblk, 256, 0, stream>>>(rowptr, eidx, g1h, dinv, b1, h1h, N);
    }

    // 3) layer 2: g2 = (f16) dinv*(h1@W2); zs = (f16, [4][N][32]) dinv*(agg+self)+b2
    {
        dim3 grid((N + 63) / 64, OUTF / 128);
        k_gemm_mfma<2, false, 7><<<grid, 256, 0, stream>>>(h1h, W2t, dinv, g2h, N, HID, OUTF);
        int nblk = (int)(((size_t)N * 64 + 255) / 256);
        k_agg2<<<nblk, 256, 0, stream>>>(rowptr, eidx, g2h, dinv, b2, zs, N);
    }

    // 4) decode: sliced partial dots (pos half, neg half) + final sum
    {
        int nblk = 4 * ((E + 127) / 128);   // per half: 4 waves x 32 edges/block
        k_decode<<<nblk, 256, 0, stream>>>(pos, neg, zs, psum, E, N, 0);
        k_decode<<<nblk, 256, 0, stream>>>(pos, neg, zs, psum, E, N, E);
        k_dsum<<<(2 * E + 255) / 256, 256, 0, stream>>>(psum, out, 2 * E);
    }
}

// Round 9
// 399.478 us; speedup vs baseline: 1.2686x; 1.0041x over previous
//
#include <hip/hip_runtime.h>
#include <hip/hip_fp16.h>

// GCN link-prediction forward. CSR aggregation, row-major fp16 gather tables
// for the aggregates (R9: 4-deep / 2-deep gather ILP — agg rows are L2-miss
// ~500cy to L3, short waves can't hide it with 2 loads in flight); XCD-sliced
// L2-resident z for decode (zs[4][N][32]), R0 TA-floor decode split into
// pos/neg launches; psum + nontemporal + dsum; batched fill/count (4 edges/
// thread, NT eidx stores); fused prep; scan2 folded into scan3.
// Inputs: x[N,256] f32, train_edges[2,E] i32, pos[2,E] i32, neg[2,E] i32,
//         W1[256,256], b1[256], W2[256,128], b2[128]  (all f32)
// Output: logits[2E] f32.

#define NFEAT 256
#define HID   256
#define OUTF  128
#define FPE   4     // edges per thread in fill/count

typedef _Float16 f16x8 __attribute__((ext_vector_type(8)));
typedef _Float16 f16x2 __attribute__((ext_vector_type(2)));
typedef float    f32x4 __attribute__((ext_vector_type(4)));

// ---------------- W transpose tile body: Wt[m][k] = (half)W[k][m] ------------
__device__ __forceinline__ void wt_body(const float* __restrict__ W,
                                        __half* __restrict__ Wt,
                                        int K, int M, int bxx, int byy) {
    __shared__ float tile[32][33];
    int k0 = bxx * 32, m0 = byy * 32;
    int tx = threadIdx.x & 31, ty = threadIdx.x >> 5;  // ty 0..7
#pragma unroll
    for (int r = 0; r < 4; ++r)
        tile[ty + r * 8][tx] = W[(size_t)(k0 + ty + r * 8) * M + m0 + tx];
    __syncthreads();
#pragma unroll
    for (int r = 0; r < 4; ++r)
        Wt[(size_t)(m0 + ty + r * 8) * K + k0 + tx] = __float2half(tile[tx][ty + r * 8]);
}

// ---------------- fused prep: wt(W1) | wt(W2) | deg=1 ----------------
__global__ __launch_bounds__(256) void k_prep(
        const float* __restrict__ W1, __half* __restrict__ W1t,
        const float* __restrict__ W2, __half* __restrict__ W2t,
        float* __restrict__ deg, int n) {
    int bid = blockIdx.x;
    if (bid < 64) { wt_body(W1, W1t, NFEAT, HID, bid & 7, bid >> 3); return; }
    bid -= 64;
    if (bid < 32) { wt_body(W2, W2t, HID, OUTF, bid & 7, bid >> 3); return; }
    bid -= 32;
    int i = bid * 256 + threadIdx.x;
    if (i < n) deg[i] = 1.0f;   // self-loop
}

// ---------------- degree count: 4 edges/thread, fire-and-forget atomics ------
__global__ __launch_bounds__(256) void k_count_deg(
        const int* __restrict__ ei, float* __restrict__ deg, int E, int stride) {
    const int t = blockIdx.x * 256 + threadIdx.x;
    int d[FPE];
#pragma unroll
    for (int k = 0; k < FPE; ++k) {
        int e = t + k * stride;
        if (e < E) d[k] = ei[E + e];
    }
#pragma unroll
    for (int k = 0; k < FPE; ++k) {
        int e = t + k * stride;
        if (e < E) atomicAdd(&deg[d[k]], 1.0f);
    }
}

// ---------------- parallel scan, pass 1: per-block exclusive scan ------------
// bsum[b] gets the RAW per-block total (scan of totals happens in k_scan3).
__global__ __launch_bounds__(1024) void k_scan1(
        const float* __restrict__ deg, int* __restrict__ excl,
        int* __restrict__ bsum, int n) {
    __shared__ int swsum[16];
    const int t = threadIdx.x, wave = t >> 6, lane = t & 63;
    const int i = blockIdx.x * 1024 + t;
    int v = (i < n) ? (int)deg[i] - 1 : 0;
    int sc = v;
#pragma unroll
    for (int off = 1; off < 64; off <<= 1) {
        int y = __shfl_up(sc, off);
        if (lane >= off) sc += y;
    }
    if (lane == 63) swsum[wave] = sc;
    __syncthreads();
    if (t < 16) {
        int w = swsum[t];
        int scw = w;
#pragma unroll
        for (int off = 1; off < 16; off <<= 1) {
            int y = __shfl_up(scw, off);
            if (t >= off) scw += y;
        }
        swsum[t] = scw - w;
        if (t == 15) bsum[blockIdx.x] = scw;
    }
    __syncthreads();
    if (i < n) excl[i] = swsum[wave] + (sc - v);
}

// ---------------- pass 2 (fused): rowptr/cursor/dinv; lanes re-scan bsum -----
__global__ __launch_bounds__(256) void k_scan3(
        float* __restrict__ deg_dinv, const int* __restrict__ excl,
        const int* __restrict__ bsum, int* __restrict__ rowptr,
        int* __restrict__ cursor, int n, int nb) {
    __shared__ int pbs[65];
    const int t = threadIdx.x;
    if (t < 64) {
        int v = (t < nb) ? bsum[t] : 0;
        int sc = v;
#pragma unroll
        for (int off = 1; off < 64; off <<= 1) {
            int y = __shfl_up(sc, off);
            if (t >= off) sc += y;
        }
        pbs[t] = sc - v;            // exclusive prefix of block totals
        if (t == 63) pbs[64] = sc;  // grand total
    }
    __syncthreads();
    int i = blockIdx.x * 256 + t;
    if (i < n) {
        int rp = excl[i] + pbs[i >> 10];
        rowptr[i] = rp;
        cursor[i] = rp;
        deg_dinv[i] = rsqrtf(deg_dinv[i]);
    } else if (i == n) {
        rowptr[n] = pbs[64];
    }
}

// ---------------- fill CSR adjacency: 4 edges/thread, NT scattered stores ----
__global__ __launch_bounds__(256) void k_fill(
        const int* __restrict__ ei, int* __restrict__ cursor,
        int* __restrict__ eidx, int E, int stride) {
    const int t = blockIdx.x * 256 + threadIdx.x;
    int s[FPE], d[FPE], p[FPE];
#pragma unroll
    for (int k = 0; k < FPE; ++k) {
        int e = t + k * stride;
        if (e < E) { s[k] = ei[e]; d[k] = ei[E + e]; }
    }
#pragma unroll
    for (int k = 0; k < FPE; ++k) {
        int e = t + k * stride;
        if (e < E) p[k] = atomicAdd(&cursor[d[k]], 1);
    }
#pragma unroll
    for (int k = 0; k < FPE; ++k) {
        int e = t + k * stride;
        if (e < E) __builtin_nontemporal_store(s[k], &eidx[p[k]]);
    }
}

// ---------------- MFMA GEMM: out = (half)(dinv[r] * A @ Wt^T) ----------------
// Block: 256 threads = 4 waves (2x2). Block tile (2*MT*16) x 128, wave (MT*16) x 64.
// A: [n][K] (f32 if AF32 else f16). Wt: [M][K] f16. K % 32 == 0.
// SWL=8 for M=256 / SWL=7 for M=128 give plain row-major output.
template <int MT, bool AF32, int SWL>
__global__ __launch_bounds__(256) void k_gemm_mfma(
        const void* __restrict__ Aptr, const __half* __restrict__ Wt,
        const float* __restrict__ dinv, __half* __restrict__ outp,
        int n, int K, int M) {
    constexpr int BM = 2 * MT * 16;
    __shared__ __half As[BM][40];      // [row][k], +8 pad: 2-way banks (free)
    __shared__ __half Bs[128][40];     // [col][k]
    __shared__ __half Cs[4][16][72];   // per-wave C repack (16B-aligned rows)

    const int t    = threadIdx.x;
    const int wave = t >> 6;
    const int lane = t & 63;
    const int row0 = blockIdx.x * BM;
    const int col0 = blockIdx.y * 128;
    const int wm = wave >> 1, wn = wave & 1;
    const int lr = lane & 15;          // fragment m/n index
    const int kq = lane >> 4;          // k-quad: k = kq*8 + j

    f32x4 acc[MT][4];
#pragma unroll
    for (int i = 0; i < MT; ++i)
#pragma unroll
        for (int j = 0; j < 4; ++j) acc[i][j] = (f32x4){0.f, 0.f, 0.f, 0.f};

    for (int k0 = 0; k0 < K; k0 += 32) {
        // ---- stage A tile: BM rows x 32 k ----
        if (AF32) {
            const float* A = (const float*)Aptr;
#pragma unroll
            for (int it = 0; it < BM * 8 / 256; ++it) {
                int q = t + it * 256;
                int r = q >> 3, c4 = q & 7;       // c4: which 4-float chunk
                int gr = min(row0 + r, n - 1);
                float4 v = *(const float4*)&A[(size_t)gr * K + k0 + c4 * 4];
                __half2* dst = (__half2*)&As[r][c4 * 4];
                dst[0] = __floats2half2_rn(v.x, v.y);
                dst[1] = __floats2half2_rn(v.z, v.w);
            }
        } else {
            const __half* A = (const __half*)Aptr;
#pragma unroll
            for (int it = 0; it < BM * 4 / 256; ++it) {
                int q = t + it * 256;
                int r = q >> 2, c8 = q & 3;       // c8: which 8-half chunk
                int gr = min(row0 + r, n - 1);
                *(float4*)&As[r][c8 * 8] = *(const float4*)&A[(size_t)gr * K + k0 + c8 * 8];
            }
        }
        // ---- stage B tile: 128 cols x 32 k from Wt ----
#pragma unroll
        for (int it = 0; it < 2; ++it) {
            int q = t + it * 256;
            int r = q >> 2, c8 = q & 3;
            *(float4*)&Bs[r][c8 * 8] = *(const float4*)&Wt[(size_t)(col0 + r) * K + k0 + c8 * 8];
        }
        __syncthreads();

        f16x8 b[4];
#pragma unroll
        for (int j = 0; j < 4; ++j)
            b[j] = *(const f16x8*)&Bs[wn * 64 + j * 16 + lr][kq * 8];
#pragma unroll
        for (int i = 0; i < MT; ++i) {
            f16x8 a = *(const f16x8*)&As[wm * MT * 16 + i * 16 + lr][kq * 8];
#pragma unroll
            for (int j = 0; j < 4; ++j)
                acc[i][j] = __builtin_amdgcn_mfma_f32_16x16x32_f16(a, b[j], acc[i][j], 0, 0, 0);
        }
        __syncthreads();
    }

    // ---- epilogue: scale by dinv, f16 convert, repack via LDS, 16-B stores ----
    constexpr int SW = 1 << SWL;
#pragma unroll
    for (int i = 0; i < MT; ++i) {
        int gr0 = row0 + wm * MT * 16 + i * 16;
        float dv[4];
#pragma unroll
        for (int r = 0; r < 4; ++r)
            dv[r] = dinv[min(gr0 + kq * 4 + r, n - 1)];
        __syncthreads();   // protect Cs reuse across i iterations
#pragma unroll
        for (int j = 0; j < 4; ++j)
#pragma unroll
            for (int r = 0; r < 4; ++r)
                Cs[wave][kq * 4 + r][j * 16 + lr] = __float2half(acc[i][j][r] * dv[r]);
        __syncthreads();
        int r1 = lane >> 3, c1 = (lane & 7) * 8;
#pragma unroll
        for (int h = 0; h < 2; ++h) {
            int grow = gr0 + r1 + h * 8;
            if (grow < n) {
                int col = col0 + wn * 64 + c1;    // multiple of 8
                size_t oidx = ((size_t)(col >> SWL) * n + grow) * SW + (col & (SW - 1));
                *(float4*)&outp[oidx] = *(const float4*)&Cs[wave][r1 + h * 8][c1];
            }
        }
    }
}

// ---------------- layer-1 aggregate: wave per node, 4-deep gather ILP --------
// g1 row-major [n][256] f16 (512B rows). lane = half(row sel) x 32 chunks x 16B.
// 8 edges per iteration, 4 independent row-gathers in flight (L2-miss ~500cy
// to L3; 2-deep was latency-bound at 58us vs ~39us TA floor).
__global__ __launch_bounds__(256) void k_agg1(
        const int* __restrict__ rowptr, const int* __restrict__ eidx,
        const __half* __restrict__ g, const float* __restrict__ dinv,
        const float* __restrict__ bias, __half* __restrict__ out, int n) {
    const int node = (int)(((size_t)blockIdx.x * blockDim.x + threadIdx.x) >> 6);
    const int lane = threadIdx.x & 63;
    const int half = lane >> 5;        // which of 2 rows this lane reads
    const int fl   = lane & 31;        // 16B chunk within row (8 halves)
    if (node >= n) return;
    const int j0  = rowptr[node];
    const int end = rowptr[node + 1];
    const int last = end - 1;          // only used when end > j0

    union U { float4 f; __half2 h[4]; };
    float acc[8] = {0.f, 0.f, 0.f, 0.f, 0.f, 0.f, 0.f, 0.f};
    {   // self row: half 0 only (avoid double count)
        if (half == 0) {
            U u; u.f = *(const float4*)&g[(size_t)node * HID + fl * 8];
#pragma unroll
            for (int k = 0; k < 4; ++k) {
                float2 v = __half22float2(u.h[k]);
                acc[k * 2] += v.x; acc[k * 2 + 1] += v.y;
            }
        }
    }
    if (j0 < end) {
        int s0 = eidx[min(j0 + half, last)];
        int s1 = eidx[min(j0 + 2 + half, last)];
        int s2 = eidx[min(j0 + 4 + half, last)];
        int s3 = eidx[min(j0 + 6 + half, last)];
        for (int j = j0; j < end; j += 8) {
            int p0 = eidx[min(j + 8 + half, last)];    // prefetch next iter's indices
            int p1 = eidx[min(j + 10 + half, last)];
            int p2 = eidx[min(j + 12 + half, last)];
            int p3 = eidx[min(j + 14 + half, last)];
            U u0, u1, u2, u3;
            u0.f = *(const float4*)&g[(size_t)s0 * HID + fl * 8];
            u1.f = *(const float4*)&g[(size_t)s1 * HID + fl * 8];
            u2.f = *(const float4*)&g[(size_t)s2 * HID + fl * 8];
            u3.f = *(const float4*)&g[(size_t)s3 * HID + fl * 8];
            if (j + half < end) {
#pragma unroll
                for (int k = 0; k < 4; ++k) {
                    float2 v = __half22float2(u0.h[k]);
                    acc[k * 2] += v.x; acc[k * 2 + 1] += v.y;
                }
            }
            if (j + 2 + half < end) {
#pragma unroll
                for (int k = 0; k < 4; ++k) {
                    float2 v = __half22float2(u1.h[k]);
                    acc[k * 2] += v.x; acc[k * 2 + 1] += v.y;
                }
            }
            if (j + 4 + half < end) {
#pragma unroll
                for (int k = 0; k < 4; ++k) {
                    float2 v = __half22float2(u2.h[k]);
                    acc[k * 2] += v.x; acc[k * 2 + 1] += v.y;
                }
            }
            if (j + 6 + half < end) {
#pragma unroll
                for (int k = 0; k < 4; ++k) {
                    float2 v = __half22float2(u3.h[k]);
                    acc[k * 2] += v.x; acc[k * 2 + 1] += v.y;
                }
            }
            s0 = p0; s1 = p1; s2 = p2; s3 = p3;
        }
    }
    // reduce across the two halves
#pragma unroll
    for (int k = 0; k < 8; ++k) acc[k] += __shfl_xor(acc[k], 32);
    if (half == 0) {
        const float sc = dinv[node];
        const int f0 = fl * 8;
        U r;
#pragma unroll
        for (int k = 0; k < 4; ++k) {
            float2 bb = *(const float2*)&bias[f0 + k * 2];
            r.h[k] = __floats2half2_rn(fmaxf(sc * acc[k * 2]     + bb.x, 0.f),
                                       fmaxf(sc * acc[k * 2 + 1] + bb.y, 0.f));
        }
        *(float4*)&out[(size_t)node * HID + f0] = r.f;
    }
}

// ---------------- layer-2 aggregate: wave per node, 2-deep gather ILP --------
// g2 row-major [n][128] f16 (256B rows) -> zs [4][n][32] f16 (sliced for decode).
// 8 edges per iteration, 2 independent 4-row gathers in flight.
__global__ __launch_bounds__(256) void k_agg2(
        const int* __restrict__ rowptr, const int* __restrict__ eidx,
        const __half* __restrict__ g, const float* __restrict__ dinv,
        const float* __restrict__ bias, __half* __restrict__ zs, int n) {
    const int node = (int)(((size_t)blockIdx.x * blockDim.x + threadIdx.x) >> 6);
    const int lane = threadIdx.x & 63;
    const int q    = lane >> 4;        // which of 4 rows this lane reads
    const int fl   = lane & 15;        // 16B chunk within row
    if (node >= n) return;
    const int j0  = rowptr[node];
    const int end = rowptr[node + 1];
    const int last = end - 1;

    union U { float4 f; __half2 h[4]; };
    float acc[8] = {0.f, 0.f, 0.f, 0.f, 0.f, 0.f, 0.f, 0.f};
    if (q == 0) {   // self row
        U u; u.f = *(const float4*)&g[(size_t)node * OUTF + fl * 8];
#pragma unroll
        for (int k = 0; k < 4; ++k) {
            float2 v = __half22float2(u.h[k]);
            acc[k * 2] += v.x; acc[k * 2 + 1] += v.y;
        }
    }
    if (j0 < end) {
        int s0 = eidx[min(j0 + q, last)];
        int s1 = eidx[min(j0 + 4 + q, last)];
        for (int j = j0; j < end; j += 8) {
            int p0 = eidx[min(j + 8 + q, last)];
            int p1 = eidx[min(j + 12 + q, last)];
            U u0, u1;
            u0.f = *(const float4*)&g[(size_t)s0 * OUTF + fl * 8];
            u1.f = *(const float4*)&g[(size_t)s1 * OUTF + fl * 8];
            if (j + q < end) {
#pragma unroll
                for (int k = 0; k < 4; ++k) {
                    float2 v = __half22float2(u0.h[k]);
                    acc[k * 2] += v.x; acc[k * 2 + 1] += v.y;
                }
            }
            if (j + 4 + q < end) {
#pragma unroll
                for (int k = 0; k < 4; ++k) {
                    float2 v = __half22float2(u1.h[k]);
                    acc[k * 2] += v.x; acc[k * 2 + 1] += v.y;
                }
            }
            s0 = p0; s1 = p1;
        }
    }
#pragma unroll
    for (int k = 0; k < 8; ++k) {
        acc[k] += __shfl_xor(acc[k], 16);
        acc[k] += __shfl_xor(acc[k], 32);
    }
    if (q == 0) {
        const float sc = dinv[node];
        const int f0 = fl * 8;              // 0,8,...,120
        U r;
#pragma unroll
        for (int k = 0; k < 4; ++k) {
            float2 bb = *(const float2*)&bias[f0 + k * 2];
            r.h[k] = __floats2half2_rn(sc * acc[k * 2]     + bb.x,
                                       sc * acc[k * 2 + 1] + bb.y);
        }
        // slice-major store: slice = f0>>5, 16B chunk stays within slice
        *(float4*)&zs[((size_t)(f0 >> 5) * n + node) * 32 + (f0 & 31)] = r.f;
    }
}

// ---------------- decode (sliced): psum[slice][e], 32 edges/wave -------------
// zs [4][n][32] f16; slice = bx & 3 (XCD-pinned, 3.2MB L2-resident).
// lane = (edge-in-wave)*2 + h; lane loads 32B of BOTH endpoint rows, 16-feat
// dot. ebase splits the launch into pos/neg halves (diagnostic + uniform branch).
__global__ __launch_bounds__(256) void k_decode(
        const int* __restrict__ pos, const int* __restrict__ neg,
        const __half* __restrict__ zs, float* __restrict__ psum,
        int E, int n, int ebase) {
    const int slice = blockIdx.x & 3;
    const int wv    = threadIdx.x >> 6;
    const int lane  = threadIdx.x & 63;
    const int eo    = lane >> 1;       // edge within wave (0..31)
    const int h     = lane & 1;        // which 32B half of the 64B rows
    int e = ebase + ((blockIdx.x >> 2) * 4 + wv) * 32 + eo;
    if (e >= 2 * E) return;
    int a, b;
    if (e < E) { a = pos[e];     b = pos[E + e]; }
    else       { a = neg[e - E]; b = neg[e];     }   // neg row1 at E + (e-E) = e
    const __half* ra = zs + ((size_t)slice * n + a) * 32 + h * 16;
    const __half* rb = zs + ((size_t)slice * n + b) * 32 + h * 16;
    union U { float4 f; f16x2 d[4]; };
    U a0, a1, b0, b1;
    a0.f = *(const float4*)&ra[0];
    a1.f = *(const float4*)&ra[8];
    b0.f = *(const float4*)&rb[0];
    b1.f = *(const float4*)&rb[8];
    float p = 0.f;
#if __has_builtin(__builtin_amdgcn_fdot2)
#pragma unroll
    for (int k = 0; k < 4; ++k) p = __builtin_amdgcn_fdot2(a0.d[k], b0.d[k], p, false);
#pragma unroll
    for (int k = 0; k < 4; ++k) p = __builtin_amdgcn_fdot2(a1.d[k], b1.d[k], p, false);
#else
#pragma unroll
    for (int k = 0; k < 4; ++k) {
        p += (float)a0.d[k][0] * (float)b0.d[k][0] + (float)a0.d[k][1] * (float)b0.d[k][1];
        p += (float)a1.d[k][0] * (float)b1.d[k][0] + (float)a1.d[k][1] * (float)b1.d[k][1];
    }
#endif
    p += __shfl_xor(p, 1);
    if (h == 0)
        __builtin_nontemporal_store(p, &psum[(size_t)slice * 2 * E + e]);
}

// ---------------- final sum over 4 slices ----------------
__global__ void k_dsum(const float* __restrict__ psum, float* __restrict__ out, int n2e) {
    int e = blockIdx.x * blockDim.x + threadIdx.x;
    if (e < n2e) {
        float p0 = __builtin_nontemporal_load(&psum[e]);
        float p1 = __builtin_nontemporal_load(&psum[(size_t)n2e + e]);
        float p2 = __builtin_nontemporal_load(&psum[2 * (size_t)n2e + e]);
        float p3 = __builtin_nontemporal_load(&psum[3 * (size_t)n2e + e]);
        out[e] = (p0 + p1) + (p2 + p3);
    }
}

extern "C" void kernel_launch(void* const* d_in, const int* in_sizes, int n_in,
                              void* d_out, int out_size, void* d_ws, size_t ws_size,
                              hipStream_t stream) {
    const float* x   = (const float*)d_in[0];
    const int*   tei = (const int*)d_in[1];
    const int*   pos = (const int*)d_in[2];
    const int*   neg = (const int*)d_in[3];
    const float* W1  = (const float*)d_in[4];
    const float* b1  = (const float*)d_in[5];
    const float* W2  = (const float*)d_in[6];
    const float* b2  = (const float*)d_in[7];
    float* out = (float*)d_out;

    const int N = in_sizes[0] / NFEAT;    // 50000
    const int E = in_sizes[1] / 2;        // 800000
    const int NB = (N + 1023) / 1024;     // scan blocks (49)

    char* ws = (char*)d_ws;
    size_t off = 0;
    __half* g1h = (__half*)(ws + off);                 // [N][256] f16 (25.6MB)
    __half* g2h = (__half*)(ws + off);                 // [N][128] f16 (g1 dead)
    __half* zs  = (__half*)(ws + off + (size_t)N * OUTF * 2);   // [4][N][32] f16
    off += (size_t)N * HID * 2;
    __half* h1h  = (__half*)(ws + off);                // [N][256] f16 (25.6MB)
    float*  psum = (float*)(ws + off);                 // [4][2E] f32 (h1 dead after gemm2)
    off += (size_t)N * HID * 2;
    float*  dinv = (float*)(ws + off);  off += (size_t)N * 4;
    int* rowptr = (int*)(ws + off);     off += (size_t)(N + 1) * 4;
    int* cursor = (int*)(ws + off);     off += (size_t)N * 4;
    int* eidx   = (int*)(ws + off);     off += (size_t)E * 4;
    __half* W1t = (__half*)(ws + off);  off += (size_t)NFEAT * HID * 2;
    __half* W2t = (__half*)(ws + off);  off += (size_t)HID * OUTF * 2;
    int* excl   = (int*)(ws + off);     off += (size_t)N * 4;
    int* bsum   = (int*)(ws + off);     off += (size_t)(NB + 1) * 4;

    // 0) fused prep: W transposes + deg init
    {
        int nbi = (N + 255) / 256;
        k_prep<<<64 + 32 + nbi, 256, 0, stream>>>(W1, W1t, W2, W2t, dinv, N);
    }

    // 1) degree -> parallel scan (scan2 fused into scan3) -> CSR fill
    {
        int nblk = (E + 256 * FPE - 1) / (256 * FPE);
        int stride = nblk * 256;
        k_count_deg<<<nblk, 256, 0, stream>>>(tei, dinv, E, stride);
        k_scan1<<<NB, 1024, 0, stream>>>(dinv, excl, bsum, N);
        k_scan3<<<(N + 256) / 256, 256, 0, stream>>>(dinv, excl, bsum, rowptr, cursor, N, NB);
        k_fill<<<nblk, 256, 0, stream>>>(tei, cursor, eidx, E, stride);
    }

    // 2) layer 1: g1 = (f16) dinv*(x@W1); h1 = (f16) relu(dinv*(agg+self)+b1)
    {
        dim3 grid((N + 127) / 128, HID / 128);
        k_gemm_mfma<4, true, 8><<<grid, 256, 0, stream>>>(x, W1t, dinv, g1h, N, NFEAT, HID);
        int nblk = (int)(((size_t)N * 64 + 255) / 256);
        k_agg1<<<nblk, 256, 0, stream>>>(rowptr, eidx, g1h, dinv, b1, h1h, N);
    }

    // 3) layer 2: g2 = (f16) dinv*(h1@W2); zs = (f16, [4][N][32]) dinv*(agg+self)+b2
    {
        dim3 grid((N + 63) / 64, OUTF / 128);
        k_gemm_mfma<2, false, 7><<<grid, 256, 0, stream>>>(h1h, W2t, dinv, g2h, N, HID, OUTF);
        int nblk = (int)(((size_t)N * 64 + 255) / 256);
        k_agg2<<<nblk, 256, 0, stream>>>(rowptr, eidx, g2h, dinv, b2, zs, N);
    }

    // 4) decode: sliced partial dots (pos half, neg half) + final sum
    {
        int nblk = 4 * ((E + 127) / 128);   // per half: 4 waves x 32 edges/block
        k_decode<<<nblk, 256, 0, stream>>>(pos, neg, zs, psum, E, N, 0);
        k_decode<<<nblk, 256, 0, stream>>>(pos, neg, zs, psum, E, N, E);
        k_dsum<<<(2 * E + 255) / 256, 256, 0, stream>>>(psum, out, 2 * E);
    }
}